// Round 1
// 187.380 us; speedup vs baseline: 1.0370x; 1.0370x over previous
//
#include <hip/hip_runtime.h>
#include <math.h>

#define B_SZ 32768
#define C_SZ 1000
#define NV4  250          // C_SZ/4 vec4 per row (4000 B per row, 16B-aligned)

typedef float fvec4 __attribute__((ext_vector_type(4)));

__constant__ float kMAGIC = 0.165745444183859f;

// ---------------- Kernel 1: fused prep + per-row loss partials ----------------
// Per-block: replicate the C=1000 reductions (8 KB, L2-hot after first touch;
// identical 256-thread strided+tree structure as the old prep_kernel so the
// scalars are bit-identical). Then one wave per row, 4 rows per wave.
//
// Margin handled as a post-correction: s_adj = s - exp(x_t) + exp(x_t - bm),
// with x_t extracted from the already-loaded registers (owner lane select),
// so no per-element cmp/sub and no scalar global re-read after the
// nontemporal (cache-bypassing) row loads.
__global__ __launch_bounds__(256) void main_kernel(const float* __restrict__ x,
                                                   const int*   __restrict__ targets,
                                                   const float* __restrict__ cls,
                                                   const float* __restrict__ diff,
                                                   const int*   __restrict__ epoch_p,
                                                   float*       __restrict__ partials) {
    __shared__ float smin[256], ssum[256], smax[256];
    const int tid = threadIdx.x;

    // ---- block-local prep reductions (same order as old prep_kernel) ----
    float mn = INFINITY, sm = 0.f, mx = -INFINITY;
    for (int c = tid; c < C_SZ; c += 256) {
        float v = cls[c];
        mn = fminf(mn, v);
        sm += v;
        mx = fmaxf(mx, diff[c]);
    }
    smin[tid] = mn; ssum[tid] = sm; smax[tid] = mx;
    __syncthreads();
    for (int s = 128; s > 0; s >>= 1) {
        if (tid < s) {
            smin[tid] = fminf(smin[tid], smin[tid + s]);
            ssum[tid] += ssum[tid + s];
            smax[tid] = fmaxf(smax[tid], smax[tid + s]);
        }
        __syncthreads();
    }
    __shared__ float sh_maxm, sh_minc, sh_wsc, sh_ee2;
    if (tid == 0) {
        const float minc = smin[0], sumc = ssum[0], maxd = smax[0];
        const float maxm = -logf(minc / sumc) - kMAGIC;
        const float maxw = 0.5f * maxd * maxd + 0.3f;   // ALPHA*d^P + BETA, P=2
        const int epoch = epoch_p[0];
        float ee2;
        if (epoch < 60)       ee2 = 0.f;
        else if (epoch >= 80) ee2 = 0.5f;               // ee=1, /2
        else                  ee2 = 0.5f * (float)(epoch - 60) / 20.0f;
        sh_maxm = maxm; sh_minc = minc; sh_wsc = maxm / maxw; sh_ee2 = ee2;
    }
    __syncthreads();
    const float maxm = sh_maxm, minc = sh_minc, wsc = sh_wsc, ee2 = sh_ee2;

    // ---- per-row loss ----
    const int lane = tid & 63;
    const int wv   = tid >> 6;
    const int gw   = blockIdx.x * 4 + wv;
    const int nw   = gridDim.x * 4;

    float acc = 0.f;
    for (int row = gw; row < B_SZ; row += nw) {
        const fvec4* __restrict__ xr = (const fvec4*)(x + (size_t)row * C_SZ);
        const int t = targets[row];                    // wave-uniform

        // Issue all 4 row loads up front (streaming, non-temporal).
        fvec4 v[4];
        #pragma unroll
        for (int k = 0; k < 4; ++k) {
            const int i4 = lane + 64 * k;
            if (i4 < NV4) v[k] = __builtin_nontemporal_load(&xr[i4]);
            else          v[k] = (fvec4){0.f, 0.f, 0.f, 0.f};
        }

        // per-row margin, same expression/order as old prep's m1[t]
        const float bm = maxm * sqrtf(minc / cls[t])
                       + (0.5f * diff[t] * diff[t] + 0.3f) * wsc * ee2;

        const int t4 = t >> 2, tm = t & 3;
        float s = 0.f, xt = 0.f;
        #pragma unroll
        for (int k = 0; k < 4; ++k) {
            const int i4 = lane + 64 * k;
            if (i4 < NV4) {
                s += __expf(v[k].x);
                s += __expf(v[k].y);
                s += __expf(v[k].z);
                s += __expf(v[k].w);
                if (i4 == t4) {                        // exactly one (lane,k) owns t
                    xt = (tm & 2) ? ((tm & 1) ? v[k].w : v[k].z)
                                  : ((tm & 1) ? v[k].y : v[k].x);
                }
            }
        }
        // wave-wide reductions (width 64): sum of exps + broadcast of x_t
        #pragma unroll
        for (int off = 32; off > 0; off >>= 1) {
            s  += __shfl_xor(s,  off);
            xt += __shfl_xor(xt, off);                 // others contributed exact 0.0
        }
        // replace exp(x_t) by exp(x_t - bm); s >> exp(x_t), no cancellation risk
        const float xadj = xt - bm;
        s = s - __expf(xt) + __expf(xadj);
        acc += __logf(s) - xadj;
    }

    __shared__ float sw[4];
    if (lane == 0) sw[wv] = acc;
    __syncthreads();
    if (tid == 0)
        partials[blockIdx.x] = sw[0] + sw[1] + sw[2] + sw[3];
}

// ---------------- Kernel 2: final reduce -> loss ----------------
__global__ void finish_kernel(const float* __restrict__ partials, int n,
                              float* __restrict__ out) {
    __shared__ float sh[256];
    const int tid = threadIdx.x;
    float s = 0.f;
    for (int i = tid; i < n; i += 256) s += partials[i];
    sh[tid] = s;
    __syncthreads();
    for (int k = 128; k > 0; k >>= 1) {
        if (tid < k) sh[tid] += sh[tid + k];
        __syncthreads();
    }
    if (tid == 0) out[0] = sh[0] / (float)B_SZ;
}

extern "C" void kernel_launch(void* const* d_in, const int* in_sizes, int n_in,
                              void* d_out, int out_size, void* d_ws, size_t ws_size,
                              hipStream_t stream) {
    const float* x       = (const float*)d_in[0];
    const int*   targets = (const int*)d_in[1];
    const float* cls     = (const float*)d_in[2];
    const float* diff    = (const float*)d_in[3];
    const int*   epoch   = (const int*)d_in[4];
    float*       out     = (float*)d_out;

    float* partials = (float*)d_ws;          // grid floats

    const int grid = 2048;                   // 8192 waves, 4 rows each
    main_kernel<<<grid, 256, 0, stream>>>(x, targets, cls, diff, epoch, partials);

    finish_kernel<<<1, 256, 0, stream>>>(partials, grid, out);
}